// Round 4
// baseline (413.019 us; speedup 1.0000x reference)
//
#include <hip/hip_runtime.h>
#include <math.h>

#define NB 4
#define NL 2048
#define NH 8
#define ND 64
#define NUPART 80
#define NUTOP 40

typedef float vfloat4 __attribute__((ext_vector_type(4)));

// ---------------------------------------------------------------------------
// Kernel 1: M[b,h,l] = max_s(q.k_s) - sum_s(q.k_s)/L over 80 sampled keys.
// One wave per (b,h,l); lane = s_local(16) x d_group(4).
// ---------------------------------------------------------------------------
__global__ __launch_bounds__(256) void k_compute_M(
    const float* __restrict__ q, const float* __restrict__ k,
    const int* __restrict__ idx, float* __restrict__ M)
{
    const int w    = blockIdx.x * 4 + (threadIdx.x >> 6);   // (b*H+h)*L + l
    const int lane = threadIdx.x & 63;
    const int l    = w & (NL - 1);
    const int bh   = w >> 11;
    const int h    = bh & (NH - 1);
    const int b    = bh >> 3;
    const int sl   = lane >> 2;   // 0..15 sample slot
    const int dg   = lane & 3;    // 0..3 d-group
    const int d0   = dg * 16;

    const float4* qv = (const float4*)(q + (((size_t)(b * NL + l) * NH + h) * ND + d0));
    const float4 q0 = qv[0], q1 = qv[1], q2 = qv[2], q3 = qv[3];

    float mx = -INFINITY, sm = 0.0f;
#pragma unroll
    for (int r = 0; r < 5; ++r) {
        const int s  = r * 16 + sl;
        const int ki = idx[l * NUPART + s];
        const float4* kv = (const float4*)(k + (((size_t)(b * NL + ki) * NH + h) * ND + d0));
        const float4 k0 = kv[0], k1 = kv[1], k2 = kv[2], k3 = kv[3];
        float p = q0.x * k0.x + q0.y * k0.y + q0.z * k0.z + q0.w * k0.w
                + q1.x * k1.x + q1.y * k1.y + q1.z * k1.z + q1.w * k1.w
                + q2.x * k2.x + q2.y * k2.y + q2.z * k2.z + q2.w * k2.w
                + q3.x * k3.x + q3.y * k3.y + q3.z * k3.z + q3.w * k3.w;
        p += __shfl_xor(p, 1);
        p += __shfl_xor(p, 2);
        mx = fmaxf(mx, p);
        sm += p;
    }
#pragma unroll
    for (int m = 4; m < 64; m <<= 1) {
        mx = fmaxf(mx, __shfl_xor(mx, m));
        sm += __shfl_xor(sm, m);
    }
    if (lane == 0) M[w] = mx - sm * (1.0f / (float)NL);
}

// ---------------------------------------------------------------------------
// Kernel 2: per (b,h), top-40 of 2048 M values (iterative argmax, lower
// index wins ties). Emits a per-row selected/not flag map for k_out.
// ---------------------------------------------------------------------------
__global__ __launch_bounds__(256) void k_topk(
    const float* __restrict__ M, int* __restrict__ rowmap)
{
    __shared__ float sM[NL];
    __shared__ float rv[4];
    __shared__ int   ri[4];
    const int bh = blockIdx.x;
    const int t  = threadIdx.x;

    for (int j = t; j < NL; j += 256) {
        sM[j] = M[bh * NL + j];
        rowmap[bh * NL + j] = 0;
    }
    __syncthreads();

    for (int it = 0; it < NUTOP; ++it) {
        float v = -INFINITY;
        int   i = NL;
        for (int j = t; j < NL; j += 256) {
            const float m = sM[j];
            if (m > v || (m == v && j < i)) { v = m; i = j; }
        }
#pragma unroll
        for (int off = 1; off < 64; off <<= 1) {
            const float ov = __shfl_xor(v, off);
            const int   oi = __shfl_xor(i, off);
            if (ov > v || (ov == v && oi < i)) { v = ov; i = oi; }
        }
        const int wid = t >> 6;
        if ((t & 63) == 0) { rv[wid] = v; ri[wid] = i; }
        __syncthreads();
        if (t == 0) {
            for (int w2 = 1; w2 < 4; ++w2) {
                if (rv[w2] > v || (rv[w2] == v && ri[w2] < i)) { v = rv[w2]; i = ri[w2]; }
            }
            rowmap[bh * NL + i] = 1;
            sM[i] = -INFINITY;
        }
        __syncthreads();
    }
}

// ---------------------------------------------------------------------------
// Kernel 3: single-sweep output writer. One block per output row (65536).
// Non-selected rows: two nontemporal 16B zero stores per thread.
// Selected rows (1280): q_row . K^T -> softmax -> nontemporal row write.
// Every output element written exactly once -> minimum possible HBM write
// traffic (512 MiB); nt stores bypass L2/L3 write-allocate.
// ---------------------------------------------------------------------------
__global__ __launch_bounds__(256) void k_out(
    const float* __restrict__ q, const float* __restrict__ k,
    const int* __restrict__ rowmap, float* __restrict__ out)
{
    const int r   = blockIdx.x;        // bh*2048 + row
    const int bh  = r >> 11;
    const int row = r & (NL - 1);
    const int b   = bh >> 3;
    const int h   = bh & 7;
    const int t   = threadIdx.x;

    vfloat4* orow = (vfloat4*)(out + (size_t)r * NL);

    if (!rowmap[r]) {
        const vfloat4 z = (vfloat4)(0.0f);
        __builtin_nontemporal_store(z, orow + t);
        __builtin_nontemporal_store(z, orow + t + 256);
        return;
    }

    __shared__ float redm[4];
    __shared__ float reds[4];
    const int lane = t & 63;
    const int wid  = t >> 6;

    // q row is wave-uniform: broadcast loads, kept in registers
    const float4* qv = (const float4*)(q + (((size_t)(b * NL + row)) * NH + h) * ND);
    float4 qr[16];
#pragma unroll
    for (int i = 0; i < 16; ++i) qr[i] = qv[i];

    float sc[8];
    float mx = -INFINITY;
#pragma unroll
    for (int j = 0; j < 8; ++j) {
        const int l = t + 256 * j;
        const float4* kv = (const float4*)(k + (((size_t)(b * NL + l)) * NH + h) * ND);
        float s = 0.0f;
#pragma unroll
        for (int i = 0; i < 16; ++i) {
            const float4 kk = kv[i];
            s += qr[i].x * kk.x + qr[i].y * kk.y + qr[i].z * kk.z + qr[i].w * kk.w;
        }
        sc[j] = s * 0.125f;   // 1/sqrt(64)
        mx = fmaxf(mx, sc[j]);
    }

#pragma unroll
    for (int off = 1; off < 64; off <<= 1) mx = fmaxf(mx, __shfl_xor(mx, off));
    if (lane == 0) redm[wid] = mx;
    __syncthreads();
    mx = fmaxf(fmaxf(redm[0], redm[1]), fmaxf(redm[2], redm[3]));

    float lsum = 0.0f;
#pragma unroll
    for (int j = 0; j < 8; ++j) {
        sc[j] = __expf(sc[j] - mx);
        lsum += sc[j];
    }
#pragma unroll
    for (int off = 1; off < 64; off <<= 1) lsum += __shfl_xor(lsum, off);
    if (lane == 0) reds[wid] = lsum;
    __syncthreads();
    const float inv = 1.0f / (reds[0] + reds[1] + reds[2] + reds[3]);

    // sc[j] is the score at column t + 256*j (coalesced per instruction)
#pragma unroll
    for (int j = 0; j < 8; ++j) {
        __builtin_nontemporal_store(sc[j] * inv, out + (size_t)r * NL + t + 256 * j);
    }
}

extern "C" void kernel_launch(void* const* d_in, const int* in_sizes, int n_in,
                              void* d_out, int out_size, void* d_ws, size_t ws_size,
                              hipStream_t stream) {
    const float* q   = (const float*)d_in[0];
    const float* k   = (const float*)d_in[1];
    const int*   idx = (const int*)d_in[2];
    float* out = (float*)d_out;

    float* Mws    = (float*)d_ws;                                    // B*H*L floats
    int*   rowmap = (int*)((char*)d_ws + (size_t)NB * NH * NL * 4);  // B*H*L ints

    k_compute_M<<<NB * NH * NL / 4, 256, 0, stream>>>(q, k, idx, Mws);
    k_topk<<<NB * NH, 256, 0, stream>>>(Mws, rowmap);
    k_out<<<NB * NH * NL, 256, 0, stream>>>(q, k, rowmap, out);
}

// Round 5
// 379.409 us; speedup vs baseline: 1.0886x; 1.0886x over previous
//
#include <hip/hip_runtime.h>
#include <math.h>

#define NB 4
#define NL 2048
#define NH 8
#define ND 64
#define NUPART 80
#define NUTOP 40
#define ZROWS1 1800   // rows [0,1800) per bh zeroed by K1; tail by K3

typedef float vfloat4 __attribute__((ext_vector_type(4)));

// ---------------------------------------------------------------------------
// K1: M[b,h,l] = max_s(q.k_s) - sum_s(q.k_s)/L over 80 sampled keys,
// fused with zero-fill of rows [0,1800) of each bh (450 MiB of the output).
// The zero stores keep the (capped ~1.7 TB/s) d_out write stream saturated
// while the latency-bound gather runs. 16384 blocks = 32 bh x 512.
// Zero slice per block: 1800 float4 (28.125 KiB), coalesced.
// ---------------------------------------------------------------------------
__global__ __launch_bounds__(256) void k_compute_M_zero(
    const float* __restrict__ q, const float* __restrict__ k,
    const int* __restrict__ idx, float* __restrict__ M,
    float* __restrict__ out)
{
    const int t = threadIdx.x;

    // ---- zero slice: block (bhz, j) owns float4s [j*1800, (j+1)*1800) of
    //      bhz's row-region [0,1800) (= float4 indices [0, 921600)) ----
    {
        const int bhz = blockIdx.x >> 9;
        const int j   = blockIdx.x & 511;
        vfloat4* o = (vfloat4*)out + (size_t)bhz * (NL * (ND * 8)) + j * 1800 + t;
        const vfloat4 z = (vfloat4)(0.0f);
#pragma unroll
        for (int i = 0; i < 7; ++i) o[i * 256] = z;   // 7*256 = 1792
        if (t < 8) o[7 * 256] = z;                    // + 8 = 1800
    }

    // ---- M computation: one wave per (b,h,l) ----
    const int w    = blockIdx.x * 4 + (t >> 6);   // (b*H+h)*L + l
    const int lane = t & 63;
    const int l    = w & (NL - 1);
    const int bh   = w >> 11;
    const int h    = bh & (NH - 1);
    const int b    = bh >> 3;
    const int sl   = lane >> 2;   // 0..15 sample slot
    const int dg   = lane & 3;    // 0..3 d-group
    const int d0   = dg * 16;

    const float4* qv = (const float4*)(q + (((size_t)(b * NL + l) * NH + h) * ND + d0));
    const float4 q0 = qv[0], q1 = qv[1], q2 = qv[2], q3 = qv[3];

    float mx = -INFINITY, sm = 0.0f;
#pragma unroll
    for (int r = 0; r < 5; ++r) {
        const int s  = r * 16 + sl;
        const int ki = idx[l * NUPART + s];
        const float4* kv = (const float4*)(k + (((size_t)(b * NL + ki) * NH + h) * ND + d0));
        const float4 k0 = kv[0], k1 = kv[1], k2 = kv[2], k3 = kv[3];
        float p = q0.x * k0.x + q0.y * k0.y + q0.z * k0.z + q0.w * k0.w
                + q1.x * k1.x + q1.y * k1.y + q1.z * k1.z + q1.w * k1.w
                + q2.x * k2.x + q2.y * k2.y + q2.z * k2.z + q2.w * k2.w
                + q3.x * k3.x + q3.y * k3.y + q3.z * k3.z + q3.w * k3.w;
        p += __shfl_xor(p, 1);
        p += __shfl_xor(p, 2);
        mx = fmaxf(mx, p);
        sm += p;
    }
#pragma unroll
    for (int m = 4; m < 64; m <<= 1) {
        mx = fmaxf(mx, __shfl_xor(mx, m));
        sm += __shfl_xor(sm, m);
    }
    if (lane == 0) M[w] = mx - sm * (1.0f / (float)NL);
}

// ---------------------------------------------------------------------------
// K2: per (b,h), top-40 of 2048 M values (iterative argmax, lower index
// wins ties). Emits both the index list (Mtop) and a per-row flag (rowmap).
// ---------------------------------------------------------------------------
__global__ __launch_bounds__(256) void k_topk(
    const float* __restrict__ M, int* __restrict__ rowmap,
    int* __restrict__ Mtop)
{
    __shared__ float sM[NL];
    __shared__ float rv[4];
    __shared__ int   ri[4];
    const int bh = blockIdx.x;
    const int t  = threadIdx.x;

    for (int j = t; j < NL; j += 256) {
        sM[j] = M[bh * NL + j];
        rowmap[bh * NL + j] = 0;
    }
    __syncthreads();

    for (int it = 0; it < NUTOP; ++it) {
        float v = -INFINITY;
        int   i = NL;
        for (int j = t; j < NL; j += 256) {
            const float m = sM[j];
            if (m > v || (m == v && j < i)) { v = m; i = j; }
        }
#pragma unroll
        for (int off = 1; off < 64; off <<= 1) {
            const float ov = __shfl_xor(v, off);
            const int   oi = __shfl_xor(i, off);
            if (ov > v || (ov == v && oi < i)) { v = ov; i = oi; }
        }
        const int wid = t >> 6;
        if ((t & 63) == 0) { rv[wid] = v; ri[wid] = i; }
        __syncthreads();
        if (t == 0) {
            for (int w2 = 1; w2 < 4; ++w2) {
                if (rv[w2] > v || (rv[w2] == v && ri[w2] < i)) { v = rv[w2]; i = ri[w2]; }
            }
            Mtop[bh * NUTOP + it] = i;
            rowmap[bh * NL + i] = 1;
            sM[i] = -INFINITY;
        }
        __syncthreads();
    }
}

// ---------------------------------------------------------------------------
// K3: per selected row (32 bh x 40): zero a slice of the per-bh tail rows
// [1800,2048) (skipping selected rows -- those get fully attn-written, and
// skipping avoids intra-kernel write races), then q_row.K^T -> softmax ->
// write the 2048-wide attn row. Zero stores issue first and drain under
// the compute.
// ---------------------------------------------------------------------------
__global__ __launch_bounds__(256) void k_attn_zero(
    const float* __restrict__ q, const float* __restrict__ k,
    const int* __restrict__ rowmap, const int* __restrict__ Mtop,
    float* __restrict__ out)
{
    const int bh  = blockIdx.x / NUTOP;
    const int ui  = blockIdx.x % NUTOP;
    const int b   = bh >> 3;
    const int h   = bh & 7;
    const int t   = threadIdx.x;
    const int row = Mtop[bh * NUTOP + ui];

    // ---- zero tail slice: ui<8 -> 7 rows, else 6 rows (8*7+32*6 = 248) ----
    {
        const vfloat4 z = (vfloat4)(0.0f);
        int r0, nr;
        if (ui < 8) { r0 = ZROWS1 + ui * 7; nr = 7; }
        else        { r0 = ZROWS1 + 56 + (ui - 8) * 6; nr = 6; }
        for (int rr = 0; rr < nr; ++rr) {
            const int rz = r0 + rr;
            if (rowmap[bh * NL + rz]) continue;   // attn block will write it
            vfloat4* o = (vfloat4*)out + ((size_t)bh * NL + rz) * (NL / 4) + t;
            o[0]   = z;
            o[256] = z;
        }
    }

    __shared__ float redm[4];
    __shared__ float reds[4];
    const int lane = t & 63;
    const int wid  = t >> 6;

    // q row is wave-uniform: broadcast loads, kept in registers
    const float4* qv = (const float4*)(q + (((size_t)(b * NL + row)) * NH + h) * ND);
    float4 qr[16];
#pragma unroll
    for (int i = 0; i < 16; ++i) qr[i] = qv[i];

    float sc[8];
    float mx = -INFINITY;
#pragma unroll
    for (int j = 0; j < 8; ++j) {
        const int l = t + 256 * j;
        const float4* kv = (const float4*)(k + (((size_t)(b * NL + l)) * NH + h) * ND);
        float s = 0.0f;
#pragma unroll
        for (int i = 0; i < 16; ++i) {
            const float4 kk = kv[i];
            s += qr[i].x * kk.x + qr[i].y * kk.y + qr[i].z * kk.z + qr[i].w * kk.w;
        }
        sc[j] = s * 0.125f;   // 1/sqrt(64)
        mx = fmaxf(mx, sc[j]);
    }

#pragma unroll
    for (int off = 1; off < 64; off <<= 1) mx = fmaxf(mx, __shfl_xor(mx, off));
    if (lane == 0) redm[wid] = mx;
    __syncthreads();
    mx = fmaxf(fmaxf(redm[0], redm[1]), fmaxf(redm[2], redm[3]));

    float lsum = 0.0f;
#pragma unroll
    for (int j = 0; j < 8; ++j) {
        sc[j] = __expf(sc[j] - mx);
        lsum += sc[j];
    }
#pragma unroll
    for (int off = 1; off < 64; off <<= 1) lsum += __shfl_xor(lsum, off);
    if (lane == 0) reds[wid] = lsum;
    __syncthreads();
    const float inv = 1.0f / (reds[0] + reds[1] + reds[2] + reds[3]);

    float* orow = out + ((size_t)bh * NL + row) * NL;
#pragma unroll
    for (int j = 0; j < 8; ++j) {
        orow[t + 256 * j] = sc[j] * inv;
    }
}

extern "C" void kernel_launch(void* const* d_in, const int* in_sizes, int n_in,
                              void* d_out, int out_size, void* d_ws, size_t ws_size,
                              hipStream_t stream) {
    const float* q   = (const float*)d_in[0];
    const float* k   = (const float*)d_in[1];
    const int*   idx = (const int*)d_in[2];
    float* out = (float*)d_out;

    float* Mws    = (float*)d_ws;                                     // 65536 f
    int*   rowmap = (int*)((char*)d_ws + (size_t)NB * NH * NL * 4);   // 65536 i
    int*   Mtop   = (int*)((char*)d_ws + (size_t)NB * NH * NL * 8);   // 1280 i

    k_compute_M_zero<<<NB * NH * NL / 4, 256, 0, stream>>>(q, k, idx, Mws, out);
    k_topk<<<NB * NH, 256, 0, stream>>>(Mws, rowmap, Mtop);
    k_attn_zero<<<NB * NH * NUTOP, 256, 0, stream>>>(q, k, rowmap, Mtop, out);
}